// Round 15
// baseline (246.528 us; speedup 1.0000x reference)
//
#include <hip/hip_runtime.h>
#include <hip/hip_bf16.h>
#include <stdint.h>

#define DM   1024
#define SEQ  2048
#define BATCH 4
#define NH   16
#define DK   64
#define NTK  16    // K=1024 / BK=64

typedef __attribute__((ext_vector_type(8))) __bf16 bf16x8;
typedef __attribute__((ext_vector_type(4))) float f32x4;
typedef __attribute__((ext_vector_type(4))) unsigned short ushort4_t;
typedef __attribute__((ext_vector_type(4))) unsigned int uint4_t;

typedef __attribute__((address_space(1))) const unsigned int GU32;
typedef __attribute__((address_space(3))) unsigned int LU32;

__device__ inline void gl_lds16(const void* g, void* l) {
  __builtin_amdgcn_global_load_lds((GU32*)g, (LU32*)l, 16, 0, 0);
}

__device__ inline f32x4 mfma16(bf16x8 a, bf16x8 b, f32x4 c) {
  return __builtin_amdgcn_mfma_f32_16x16x32_bf16(a, b, c, 0, 0, 0);
}

// AGPR-accumulator MFMA: "+a" pins acc in the accumulator file so the 128-VGPR
// cap of 512-thread blocks (R13/R14 lesson) doesn't force spills.
__device__ inline void mfma16a(bf16x8 a, bf16x8 b, f32x4& c) {
  asm("v_mfma_f32_16x16x32_bf16 %0, %1, %2, %0" : "+a"(c) : "v"(a), "v"(b));
}

__device__ inline unsigned short f2bf(float f) {
  unsigned u = __float_as_uint(f);
  u += 0x7fffu + ((u >> 16) & 1u);
  return (unsigned short)(u >> 16);
}

__device__ inline unsigned cvt_pk_bf16(float a, float b) {
  unsigned r;
  asm("v_cvt_pk_bf16_f32 %0, %1, %2" : "=v"(r) : "v"(a), "v"(b));
  return r;  // lo = bf16(a), hi = bf16(b)
}

__device__ inline float fexp2(float x) {
  float r;
  asm("v_exp_f32 %0, %1" : "=v"(r) : "v"(x));
  return r;
}

// element-space chunk swizzle (128x128 GEMM tiles)
__device__ inline int swz_of(int r) { return ((r & 6) << 2) | ((r & 1) << 5); }
// byte-space version (attn tiles + 8-phase GEMM): permutes 16B chunks in 128B row
__device__ inline int bswz(int r) { return ((r & 6) << 3) | ((r & 1) << 6); }

#define BAR_SYNC() do { \
  __builtin_amdgcn_sched_barrier(0); \
  __builtin_amdgcn_s_barrier(); \
  asm volatile("" ::: "memory"); \
  __builtin_amdgcn_sched_barrier(0); } while(0)
#define LGKM0() do { \
  asm volatile("s_waitcnt lgkmcnt(0)" ::: "memory"); \
  __builtin_amdgcn_sched_barrier(0); } while(0)

// ---------------- prep: fp32 -> bf16 conversions + rope table ----------------
__global__ void prep_kernel(const float* __restrict__ x,
                            const float* __restrict__ wq, const float* __restrict__ wk,
                            const float* __restrict__ wv, const float* __restrict__ wo,
                            const int* __restrict__ tp,
                            unsigned short* __restrict__ xbf,
                            unsigned short* __restrict__ wbf,
                            float2* __restrict__ tab)
{
  const int NX4 = (BATCH*SEQ*DM)/4;
  const int NW4 = (DM*DM)/4;
  int idx = blockIdx.x*256 + threadIdx.x;
  if (idx < NX4) {
    float4 v = ((const float4*)x)[idx];
    ushort4_t o; o[0]=f2bf(v.x); o[1]=f2bf(v.y); o[2]=f2bf(v.z); o[3]=f2bf(v.w);
    ((ushort4_t*)xbf)[idx] = o;
  } else if (idx < NX4 + 4*NW4) {
    int t = idx - NX4;
    int wsel = t >> 18;
    int off = t & (NW4-1);
    const float* src = (wsel==0) ? wq : (wsel==1) ? wk : (wsel==2) ? wv : wo;
    float4 v = ((const float4*)src)[off];
    ushort4_t o; o[0]=f2bf(v.x); o[1]=f2bf(v.y); o[2]=f2bf(v.z); o[3]=f2bf(v.w);
    ((ushort4_t*)wbf)[wsel*NW4 + off] = o;
  } else {
    int t = idx - NX4 - 4*NW4;
    if (t < SEQ*32) {
      int s = t >> 5, i = t & 31;
      float invf = exp2f(-(float)i * (13.287712379549449f/32.0f));
      float ang = (float)tp[s] * invf;
      float sn, cs; sincosf(ang, &sn, &cs);
      tab[t] = make_float2(cs, sn);
    }
  }
}

// ---------------- QKV GEMM: 256x256 8-phase counted-vmcnt, AGPR accumulator ---
// R13/R14: 512-thread blocks cap VGPRs at 128 -> acc[8][4] spilled (WRITE 84MB).
// Fix: acc lives in AGPRs via inline-asm mfma ("+a") -- VGPRs hold only
// fragments+addresses (~110), AGPRs hold the 128 acc regs. HK's pattern.
__global__ __launch_bounds__(512, 1)
void gemm8(const unsigned short* __restrict__ A,
           const unsigned short* __restrict__ Wall,
           unsigned short* __restrict__ qbf,
           unsigned short* __restrict__ kbf,
           unsigned short* __restrict__ vt,
           const float2* __restrict__ tab)
{
  __shared__ __align__(16) char lds[131072];
  const int tid = threadIdx.x;
  const int bid = blockIdx.x;
  const int sel = bid >> 7;
  const int rb = bid & 127;
  const int xcd = rb & 7, idx = rb >> 3;
  const int mt = xcd*4 + (idx>>2), nt = idx & 3;
  const unsigned short* Bw = Wall + (size_t)sel*DM*DM;
  const int a0 = mt*256, b0 = nt*256;
  const int w = tid>>6, lane = tid&63, ln = lane&15, g = lane>>4;
  const int wm = (w>>2)*128, wn = (w&3)*64;

  // staging sources: thread covers rows r0, r0+64 of each 128-row half
  const int r0 = tid >> 3;            // 0..63
  const int csw = ((tid & 7) * 16) ^ bswz(r0);
  const char* pA = (const char*)A  + ((size_t)(a0 + r0))*2048 + csw;
  const char* pB = (const char*)Bw + ((size_t)(b0 + r0))*2048 + csw;

  auto stage = [&](int hh) {
    int T = hh>>2, j = hh&3;   // j: 0=B-h0 1=B-h1 2=A-h0 3=A-h1
    const char* s = ((j<2) ? pB : pA) + (size_t)(j&1)*262144 + (size_t)T*128;
    char* d = lds + (T&1)*65536 + ((j<2) ? (32768 + j*16384) : ((j-2)*16384))
              + tid*16;
    gl_lds16(s,          d);
    gl_lds16(s + 131072, d + 8192);
  };

  const int swz = bswz(ln);
  const int arow = (wm + ln)*128;
  const int brow = 32768 + (wn + ln)*128;

  f32x4 acc[8][4];
  #pragma unroll
  for (int i=0;i<8;i++)
    #pragma unroll
    for (int j=0;j<4;j++) acc[i][j] = (f32x4){0.f,0.f,0.f,0.f};

  // prologue: halves 0..5 (tile0 complete + tile1 B halves)
  #pragma unroll
  for (int hh = 0; hh < 6; ++hh) stage(hh);
  asm volatile("s_waitcnt vmcnt(4)" ::: "memory");
  BAR_SYNC();

  int hptr = 6;
  for (int U = 0; U < 16; ++U) {
    char* sb = lds + (U&1)*65536;
    bf16x8 Afr[4][2], Bfr[4][2];

    // ---- phase 1: read A m0-3 + B n0-1; mfma quad (m0-3, n0-1) ----
    #pragma unroll
    for (int mi=0;mi<4;++mi)
      #pragma unroll
      for (int kh=0;kh<2;++kh)
        Afr[mi][kh] = *(const bf16x8*)(sb + arow + mi*2048 + (((kh<<6)|(g<<4)) ^ swz));
    #pragma unroll
    for (int nf=0;nf<2;++nf)
      #pragma unroll
      for (int kh=0;kh<2;++kh)
        Bfr[nf][kh] = *(const bf16x8*)(sb + brow + nf*2048 + (((kh<<6)|(g<<4)) ^ swz));
    if (hptr < 64) stage(hptr++);
    BAR_SYNC();
    LGKM0();
    __builtin_amdgcn_s_setprio(1);
    #pragma unroll
    for (int mi=0;mi<4;++mi)
      #pragma unroll
      for (int nf=0;nf<2;++nf)
        #pragma unroll
        for (int kh=0;kh<2;++kh)
          mfma16a(Afr[mi][kh], Bfr[nf][kh], acc[mi][nf]);
    __builtin_amdgcn_s_setprio(0);
    BAR_SYNC();

    // ---- phase 2: read B n2-3; mfma quad (m0-3, n2-3) ----
    #pragma unroll
    for (int nf=2;nf<4;++nf)
      #pragma unroll
      for (int kh=0;kh<2;++kh)
        Bfr[nf][kh] = *(const bf16x8*)(sb + brow + nf*2048 + (((kh<<6)|(g<<4)) ^ swz));
    if (hptr < 64) stage(hptr++);
    BAR_SYNC();
    LGKM0();
    __builtin_amdgcn_s_setprio(1);
    #pragma unroll
    for (int mi=0;mi<4;++mi)
      #pragma unroll
      for (int nf=2;nf<4;++nf)
        #pragma unroll
        for (int kh=0;kh<2;++kh)
          mfma16a(Afr[mi][kh], Bfr[nf][kh], acc[mi][nf]);
    __builtin_amdgcn_s_setprio(0);
    BAR_SYNC();

    // ---- phase 3: read A m4-7; mfma quad (m4-7, n0-1) ----
    #pragma unroll
    for (int mi=0;mi<4;++mi)
      #pragma unroll
      for (int kh=0;kh<2;++kh)
        Afr[mi][kh] = *(const bf16x8*)(sb + arow + 8192 + mi*2048 + (((kh<<6)|(g<<4)) ^ swz));
    if (hptr < 64) stage(hptr++);
    BAR_SYNC();
    LGKM0();
    __builtin_amdgcn_s_setprio(1);
    #pragma unroll
    for (int mi=0;mi<4;++mi)
      #pragma unroll
      for (int nf=0;nf<2;++nf)
        #pragma unroll
        for (int kh=0;kh<2;++kh)
          mfma16a(Afr[mi][kh], Bfr[nf][kh], acc[4+mi][nf]);
    __builtin_amdgcn_s_setprio(0);
    BAR_SYNC();

    // ---- phase 4: no reads; mfma quad (m4-7, n2-3); counted vmcnt ----
    if (hptr < 64) stage(hptr++);
    __builtin_amdgcn_s_setprio(1);
    #pragma unroll
    for (int mi=0;mi<4;++mi)
      #pragma unroll
      for (int nf=2;nf<4;++nf)
        #pragma unroll
        for (int kh=0;kh<2;++kh)
          mfma16a(Afr[mi][kh], Bfr[nf][kh], acc[4+mi][nf]);
    __builtin_amdgcn_s_setprio(0);
    if (U < 14)       asm volatile("s_waitcnt vmcnt(4)" ::: "memory");
    else if (U == 14) asm volatile("s_waitcnt vmcnt(0)" ::: "memory");
    BAR_SYNC();
  }

  // ---- epilogues (verified formulas, 8x4 fragment loops) ----
  if (sel == 2) {
    #pragma unroll
    for (int mi=0;mi<8;++mi) {
      int m0 = a0 + wm + mi*16 + g*4;
      int bb = m0>>11, s0 = m0&2047;
      #pragma unroll
      for (int nf=0;nf<4;++nf) {
        int n = b0 + wn + nf*16 + ln;
        int h = n>>6, d = n&63;
        ushort4_t o4;
        #pragma unroll
        for (int jj=0;jj<4;++jj) o4[jj] = f2bf(acc[mi][nf][jj]);
        *(ushort4_t*)&vt[(((size_t)bb*NH + h)*DK + d)*SEQ + s0] = o4;
      }
    }
  } else {
    unsigned short* dst = sel ? kbf : qbf;
    const float qs = sel ? 1.0f : 0.1803368802f;   // 1/8 * log2(e) folded into Q
    #pragma unroll
    for (int nf=0;nf<4;++nf) {
      int n = b0 + wn + nf*16 + ln;
      int h = n>>6, d = n&63, di = d>>1, par = d&1;
      #pragma unroll
      for (int mi=0;mi<8;++mi) {
        #pragma unroll
        for (int jj=0;jj<4;++jj) {
          int m = a0 + wm + mi*16 + g*4 + jj;
          int bb = m>>11, s = m&2047;
          float v = acc[mi][nf][jj];
          float pv = __shfl_xor(v, 1);
          float2 cssn = tab[s*32 + di];
          float r = par ? (v*cssn.x + pv*cssn.y) : (v*cssn.x - pv*cssn.y);
          dst[((size_t)(bb*NH + h)*SEQ + s)*DK + d] = f2bf(r*qs);
        }
      }
    }
  }
}

// ---------------- O-proj GEMM: counted-vmcnt double-buffered 128x128 ---------
template<int MODE>
__global__ __launch_bounds__(256, 2)
void gemm_db(const unsigned short* __restrict__ A,
             const unsigned short* __restrict__ Wall,
             float* __restrict__ ofp)
{
  __shared__ __align__(16) char lds[65536];
  const int tid = threadIdx.x;
  const int bid = blockIdx.x;
  int xcd = bid & 7, idx = bid >> 3;
  int mt = xcd*8 + (idx >> 3), nt = idx & 7;
  const unsigned short* Bm = Wall + (size_t)3*DM*DM;
  const int a0 = mt*128, b0r = nt*128;
  const int w = tid>>6, lane = tid&63, ln = lane&15, g = lane>>4;
  const int wm = (w>>1)*64, wn = (w&1)*64;

  const char* src[8];
  {
    int rr = tid >> 3;
    int c  = (tid & 7) * 8;
    #pragma unroll
    for (int i = 0; i < 4; ++i) {
      int r_ = i*32 + rr;
      int cs = c ^ swz_of(r_);
      src[i]   = (const char*)(A  + (size_t)(a0  + r_)*DM + cs);
      src[i+4] = (const char*)(Bm + (size_t)(b0r + r_)*DM + cs);
    }
  }

  int offA[4], offB[4];
  #pragma unroll
  for (int m = 0; m < 4; ++m) {
    int R  = wm + m*16 + ln;
    offA[m] = R*128 + ((g*8 ^ swz_of(R)) * 2);
    int Rb = wn + m*16 + ln;
    offB[m] = 16384 + Rb*128 + ((g*8 ^ swz_of(Rb)) * 2);
  }

  f32x4 acc[4][4];
  #pragma unroll
  for (int i=0;i<4;i++)
    #pragma unroll
    for (int j=0;j<4;j++) acc[i][j] = (f32x4){0.f,0.f,0.f,0.f};

  #pragma unroll
  for (int i = 0; i < 8; ++i) gl_lds16(src[i],       lds +         i*4096 + tid*16);
  #pragma unroll
  for (int i = 0; i < 8; ++i) gl_lds16(src[i] + 128, lds + 32768 + i*4096 + tid*16);

  for (int t = 0; t < NTK; ++t) {
    char* sb = lds + (t & 1) * 32768;
    if (t < NTK-1) asm volatile("s_waitcnt vmcnt(8)" ::: "memory");
    else           asm volatile("s_waitcnt vmcnt(0)" ::: "memory");
    BAR_SYNC();

    bf16x8 fa[4][2], fb[4][2];
    #pragma unroll
    for (int m = 0; m < 4; ++m) {
      fa[m][0] = *(const bf16x8*)(sb + offA[m]);
      fa[m][1] = *(const bf16x8*)(sb + (offA[m] ^ 64));
      fb[m][0] = *(const bf16x8*)(sb + offB[m]);
      fb[m][1] = *(const bf16x8*)(sb + (offB[m] ^ 64));
    }
    LGKM0();
    BAR_SYNC();

    if (t + 2 < NTK) {
      const int kb = (t + 2) * 128;
      #pragma unroll
      for (int i = 0; i < 8; ++i)
        gl_lds16(src[i] + kb, sb + i*4096 + tid*16);
    }
    __builtin_amdgcn_s_setprio(1);
    #pragma unroll
    for (int h = 0; h < 2; ++h)
      #pragma unroll
      for (int m = 0; m < 4; ++m)
        #pragma unroll
        for (int n = 0; n < 4; ++n)
          acc[m][n] = mfma16(fa[m][h], fb[n][h], acc[m][n]);
    __builtin_amdgcn_s_setprio(0);
  }

  #pragma unroll
  for (int i=0;i<4;i++) {
    int m = a0 + wm + i*16 + g*4;
    #pragma unroll
    for (int jn=0;jn<4;jn++) {
      int n = b0r + wn + jn*16 + ln;
      #pragma unroll
      for (int j=0;j<4;j++)
        ofp[(size_t)(m+j)*DM + n] = acc[i][jn][j];
    }
  }
}

// ---------------- flash attention: static-max softmax (R12, unchanged) --------
__global__ __launch_bounds__(128, 2)
void attn_fa(const unsigned short* __restrict__ qbf,
             const unsigned short* __restrict__ kbf,
             const unsigned short* __restrict__ vtg,
             unsigned short* __restrict__ attnbf)
{
  __shared__ __align__(16) char kv_lds[32768];
  __shared__ __align__(16) char pl_lds[4096];
  const int bh = blockIdx.x, pr = blockIdx.y;
  const int qbA = 31 - pr;
  const int NTa = qbA + 1;
  const int NTtot = 33;
  const int tid = threadIdx.x, w = tid>>6, lane = tid&63, ln = lane&15, g = lane>>4;
  const int bb = bh>>4, h = bh&15;

  uint4_t ov = {0x3F803F80u, 0x3F803F80u, 0x3F803F80u, 0x3F803F80u};
  const bf16x8 ones = *(bf16x8*)&ov;

  const int rr = tid >> 3;
  const int cb = (tid & 7) * 16;
  const char* ks[4]; const char* vs[4];
  #pragma unroll
  for (int i = 0; i < 4; ++i) {
    int row = rr + i*16;
    ks[i] = (const char*)(kbf + ((size_t)bh*SEQ + row)*DK) + (cb ^ bswz(row));
    vs[i] = (const char*)(vtg + ((size_t)bh*DK  + row)*SEQ) + (cb ^ bswz(row));
  }

  const int ok0 = (g*16) ^ bswz(ln);
  char* plw = pl_lds + w*2048 + ln*128;
  const int plswz = (ln & 7) << 4;

  #pragma unroll
  for (int i = 0; i < 4; ++i) {
    gl_lds16(ks[i], kv_lds + i*2048 + tid*16);
    gl_lds16(vs[i], kv_lds + 8192 + i*2048 + tid*16);
  }
  #pragma unroll
  for (int i = 0; i < 4; ++i) {
    gl_lds16(ks[i] + 8192, kv_lds + 16384 + i*2048 + tid*16);
    gl_lds16(vs[i] + 128,  kv_lds + 16384 + 8192 + i*2048 + tid*16);
  }

  int q0a = qbA*64 + w*32;
  int q0b = q0a + 16;
  const unsigned short* qrA = qbf + ((size_t)bh*SEQ + q0a + ln)*DK;
  const unsigned short* qrB = qbf + ((size_t)bh*SEQ + q0b + ln)*DK;
  bf16x8 qa0 = *(const bf16x8*)(qrA + g*8);
  bf16x8 qa1 = *(const bf16x8*)(qrA + 32 + g*8);
  bf16x8 qb0 = *(const bf16x8*)(qrB + g*8);
  bf16x8 qb1 = *(const bf16x8*)(qrB + 32 + g*8);

  f32x4 oA[4], oB[4], osA, osB;
  #pragma unroll
  for (int f=0;f<4;f++) { oA[f] = (f32x4){0,0,0,0}; oB[f] = (f32x4){0,0,0,0}; }
  osA = (f32x4){0,0,0,0}; osB = (f32x4){0,0,0,0};

  for (int u = 0; u < NTtot; ++u) {
    const int tloc  = (u < NTa) ? u : u - NTa;
    const int NTcur = (u < NTa) ? NTa : NTtot - NTa;
    char* sb = kv_lds + (u & 1) * 16384;
    if (u < NTtot-1) asm volatile("s_waitcnt vmcnt(8)" ::: "memory");
    else             asm volatile("s_waitcnt vmcnt(0)" ::: "memory");
    BAR_SYNC();

    bf16x8 kf[4][2], vfr[4][2];
    #pragma unroll
    for (int a=0;a<4;a++) {
      kf[a][0]  = *(const bf16x8*)(sb + a*2048 + (ok0 ^  0) + ln*128);
      kf[a][1]  = *(const bf16x8*)(sb + a*2048 + (ok0 ^ 64) + ln*128);
      vfr[a][0] = *(const bf16x8*)(sb + 8192 + a*2048 + (ok0 ^  0) + ln*128);
      vfr[a][1] = *(const bf16x8*)(sb + 8192 + a*2048 + (ok0 ^ 64) + ln*128);
    }
    LGKM0();
    BAR_SYNC();

    if (u + 2 < NTtot) {
      const int t2 = (u + 2 < NTa) ? u + 2 : u + 2 - NTa;
      const size_t kO = (size_t)t2*8192, vO = (size_t)t2*128;
      #pragma unroll
      for (int i = 0; i < 4; ++i) {
        gl_lds16(ks[i] + kO, sb + i*2048 + tid*16);
        gl_lds16(vs[i] + vO, sb + 8192 + i*2048 + tid*16);
      }
    }

    if (u == NTa) {
      #pragma unroll
      for (int j=0;j<4;j++) {
        float liA = 1.0f / osA[j];
        float liB = 1.0f / osB[j];
        int sA = q0a + g*4 + j, sB = q0b + g*4 + j;
        #pragma unroll
        for (int f=0;f<4;f++) {
          attnbf[((size_t)bb*SEQ + sA)*DM + h*DK + f*16 + ln] = f2bf(oA[f][j]*liA);
          attnbf[((size_t)bb*SEQ + sB)*DM + h*DK + f*16 + ln] = f2bf(oB[f][j]*liB);
        }
      }
      q0a = pr*64 + w*32;
      q0b = q0a + 16;
      const unsigned short* qa = qbf + ((size_t)bh*SEQ + q0a + ln)*DK;
      const unsigned short* qb = qbf + ((size_t)bh*SEQ + q0b + ln)*DK;
      qa0 = *(const bf16x8*)(qa + g*8);
      qa1 = *(const bf16x8*)(qa + 32 + g*8);
      qb0 = *(const bf16x8*)(qb + g*8);
      qb1 = *(const bf16x8*)(qb + 32 + g*8);
      #pragma unroll
      for (int f=0;f<4;f++) { oA[f] = (f32x4){0,0,0,0}; oB[f] = (f32x4){0,0,0,0}; }
      osA = (f32x4){0,0,0,0}; osB = (f32x4){0,0,0,0};
    }

    f32x4 saA[4], saB[4];
    __builtin_amdgcn_s_setprio(1);
    #pragma unroll
    for (int kvf=0;kvf<4;kvf++) {
      f32x4 za = (f32x4){0,0,0,0};
      za = mfma16(kf[kvf][0], qa0, za);
      za = mfma16(kf[kvf][1], qa1, za);
      saA[kvf] = za;
      f32x4 zb = (f32x4){0,0,0,0};
      zb = mfma16(kf[kvf][0], qb0, zb);
      zb = mfma16(kf[kvf][1], qb1, zb);
      saB[kvf] = zb;
    }
    __builtin_amdgcn_s_setprio(0);

    const bool diag = (tloc == NTcur-1);

    {
      if (diag) {
        int thr = q0a + ln - tloc*64 - g*4;
        #pragma unroll
        for (int kvf=0;kvf<4;kvf++)
          #pragma unroll
          for (int j=0;j<4;j++)
            if (kvf*16 + j > thr) saA[kvf][j] = -1e30f;
      }
      #pragma unroll
      for (int kvf=0;kvf<4;kvf++) {
        float p0 = fexp2(saA[kvf][0]);
        float p1 = fexp2(saA[kvf][1]);
        float p2 = fexp2(saA[kvf][2]);
        float p3 = fexp2(saA[kvf][3]);
        uint2 pk;
        pk.x = cvt_pk_bf16(p0, p1);
        pk.y = cvt_pk_bf16(p2, p3);
        *(uint2*)(plw + ((kvf*32 + g*8) ^ plswz)) = pk;
      }
      asm volatile("s_waitcnt lgkmcnt(0)" ::: "memory");
      __builtin_amdgcn_sched_barrier(0);
      #pragma unroll
      for (int c=0;c<2;c++) {
        bf16x8 pfA = *(const bf16x8*)(plw + ((c*64 + g*16) ^ plswz));
        #pragma unroll
        for (int f=0;f<4;f++)
          oA[f] = mfma16(pfA, vfr[f][c], oA[f]);
        osA = mfma16(pfA, ones, osA);
      }
    }

    {
      if (diag) {
        int thr = q0b + ln - tloc*64 - g*4;
        #pragma unroll
        for (int kvf=0;kvf<4;kvf++)
          #pragma unroll
          for (int j=0;j<4;j++)
            if (kvf*16 + j > thr) saB[kvf][j] = -1e30f;
      }
      #pragma unroll
      for (int kvf=0;kvf<4;kvf++) {
        float p0 = fexp2(saB[kvf][0]);
        float p1 = fexp2(saB[kvf][1]);
        float p2 = fexp2(saB[kvf][2]);
        float p3 = fexp2(saB[kvf][3]);
        uint2 pk;
        pk.x = cvt_pk_bf16(p0, p1);
        pk.y = cvt_pk_bf16(p2, p3);
        *(uint2*)(plw + ((kvf*32 + g*8) ^ plswz)) = pk;
      }
      asm volatile("s_waitcnt lgkmcnt(0)" ::: "memory");
      __builtin_amdgcn_sched_barrier(0);
      __builtin_amdgcn_s_setprio(1);
      #pragma unroll
      for (int c=0;c<2;c++) {
        bf16x8 pfB = *(const bf16x8*)(plw + ((c*64 + g*16) ^ plswz));
        #pragma unroll
        for (int f=0;f<4;f++)
          oB[f] = mfma16(pfB, vfr[f][c], oB[f]);
        osB = mfma16(pfB, ones, osB);
      }
      __builtin_amdgcn_s_setprio(0);
    }
  }

  #pragma unroll
  for (int j=0;j<4;j++) {
    float liA = 1.0f / osA[j];
    float liB = 1.0f / osB[j];
    int sA = q0a + g*4 + j, sB = q0b + g*4 + j;
    #pragma unroll
    for (int f=0;f<4;f++) {
      attnbf[((size_t)bb*SEQ + sA)*DM + h*DK + f*16 + ln] = f2bf(oA[f][j]*liA);
      attnbf[((size_t)bb*SEQ + sB)*DM + h*DK + f*16 + ln] = f2bf(oB[f][j]*liB);
    }
  }
}

// ---------------- launch ----------------
extern "C" void kernel_launch(void* const* d_in, const int* in_sizes, int n_in,
                              void* d_out, int out_size, void* d_ws, size_t ws_size,
                              hipStream_t stream)
{
  const float* x  = (const float*)d_in[0];
  const float* wq = (const float*)d_in[1];
  const float* wk = (const float*)d_in[2];
  const float* wv = (const float*)d_in[3];
  const float* wo = (const float*)d_in[4];
  const int*   tp = (const int*)d_in[5];

  const size_t XB = (size_t)BATCH*SEQ*DM*2;
  const size_t WB = (size_t)DM*DM*2;

  char* ws = (char*)d_ws;
  unsigned short* xbf = (unsigned short*)(ws);
  unsigned short* qbf = (unsigned short*)(ws + XB);
  unsigned short* kbf = (unsigned short*)(ws + 2*XB);
  unsigned short* vt  = (unsigned short*)(ws + 3*XB);
  unsigned short* abf = (unsigned short*)(ws + 4*XB);
  unsigned short* wbf = (unsigned short*)(ws + 5*XB);
  float2* tab = (float2*)(ws + 5*XB + 4*WB);

  prep_kernel<<<12544, 256, 0, stream>>>(x, wq, wk, wv, wo, tp, xbf, wbf, tab);

  // QKV: 256x256 8-phase counted-vmcnt GEMM, AGPR accumulator
  gemm8<<<384, 512, 0, stream>>>(xbf, wbf, qbf, kbf, vt, tab);
  // attention
  attn_fa<<<dim3(64,16), 128, 0, stream>>>(qbf, kbf, vt, abf);
  // O-proj
  gemm_db<1><<<512, 256, 0, stream>>>(abf, wbf, (float*)d_out);
}

// Round 16
// 169.442 us; speedup vs baseline: 1.4549x; 1.4549x over previous
//
#include <hip/hip_runtime.h>
#include <hip/hip_bf16.h>
#include <stdint.h>

#define DM   1024
#define SEQ  2048
#define BATCH 4
#define NH   16
#define DK   64
#define NTK  16    // K=1024 / BK=64 (gemm_db)
#define NT32 32    // K=1024 / BK=32 (gemm_qkv32)

typedef __attribute__((ext_vector_type(8))) __bf16 bf16x8;
typedef __attribute__((ext_vector_type(4))) float f32x4;
typedef __attribute__((ext_vector_type(4))) unsigned short ushort4_t;
typedef __attribute__((ext_vector_type(4))) unsigned int uint4_t;

typedef __attribute__((address_space(1))) const unsigned int GU32;
typedef __attribute__((address_space(3))) unsigned int LU32;

__device__ inline void gl_lds16(const void* g, void* l) {
  __builtin_amdgcn_global_load_lds((GU32*)g, (LU32*)l, 16, 0, 0);
}

__device__ inline f32x4 mfma16(bf16x8 a, bf16x8 b, f32x4 c) {
  return __builtin_amdgcn_mfma_f32_16x16x32_bf16(a, b, c, 0, 0, 0);
}

__device__ inline unsigned short f2bf(float f) {
  unsigned u = __float_as_uint(f);
  u += 0x7fffu + ((u >> 16) & 1u);
  return (unsigned short)(u >> 16);
}

__device__ inline unsigned cvt_pk_bf16(float a, float b) {
  unsigned r;
  asm("v_cvt_pk_bf16_f32 %0, %1, %2" : "=v"(r) : "v"(a), "v"(b));
  return r;  // lo = bf16(a), hi = bf16(b)
}

__device__ inline float fexp2(float x) {
  float r;
  asm("v_exp_f32 %0, %1" : "=v"(r) : "v"(x));
  return r;
}

// element-space chunk swizzle (128x128 BK=64 GEMM tiles)
__device__ inline int swz_of(int r) { return ((r & 6) << 2) | ((r & 1) << 5); }
// byte-space version (attn tiles)
__device__ inline int bswz(int r) { return ((r & 6) << 3) | ((r & 1) << 6); }

#define BAR_SYNC() do { \
  __builtin_amdgcn_sched_barrier(0); \
  __builtin_amdgcn_s_barrier(); \
  asm volatile("" ::: "memory"); \
  __builtin_amdgcn_sched_barrier(0); } while(0)
#define LGKM0() do { \
  asm volatile("s_waitcnt lgkmcnt(0)" ::: "memory"); \
  __builtin_amdgcn_sched_barrier(0); } while(0)

// ---------------- prep: fp32 -> bf16 conversions + rope table ----------------
__global__ void prep_kernel(const float* __restrict__ x,
                            const float* __restrict__ wq, const float* __restrict__ wk,
                            const float* __restrict__ wv, const float* __restrict__ wo,
                            const int* __restrict__ tp,
                            unsigned short* __restrict__ xbf,
                            unsigned short* __restrict__ wbf,
                            float2* __restrict__ tab)
{
  const int NX4 = (BATCH*SEQ*DM)/4;
  const int NW4 = (DM*DM)/4;
  int idx = blockIdx.x*256 + threadIdx.x;
  if (idx < NX4) {
    float4 v = ((const float4*)x)[idx];
    ushort4_t o; o[0]=f2bf(v.x); o[1]=f2bf(v.y); o[2]=f2bf(v.z); o[3]=f2bf(v.w);
    ((ushort4_t*)xbf)[idx] = o;
  } else if (idx < NX4 + 4*NW4) {
    int t = idx - NX4;
    int wsel = t >> 18;
    int off = t & (NW4-1);
    const float* src = (wsel==0) ? wq : (wsel==1) ? wk : (wsel==2) ? wv : wo;
    float4 v = ((const float4*)src)[off];
    ushort4_t o; o[0]=f2bf(v.x); o[1]=f2bf(v.y); o[2]=f2bf(v.z); o[3]=f2bf(v.w);
    ((ushort4_t*)wbf)[wsel*NW4 + off] = o;
  } else {
    int t = idx - NX4 - 4*NW4;
    if (t < SEQ*32) {
      int s = t >> 5, i = t & 31;
      float invf = exp2f(-(float)i * (13.287712379549449f/32.0f));
      float ang = (float)tp[s] * invf;
      float sn, cs; sincosf(ang, &sn, &cs);
      tab[t] = make_float2(cs, sn);
    }
  }
}

// ---------------- QKV GEMM: m97-geometry BK=32, 32KB LDS, 4 blocks/CU ---------
// 128x128 tile, 2 slots x (A 8KB + B 8KB); counted vmcnt depth-2 prefetch;
// linear 64B-row LDS (m97's own layout, 874-912 TF proven); sel-major
// XCD-chunked grid 1536. Epilogues: rope->q/k (sel 0/1), transpose->v^T (sel 2).
__global__ __launch_bounds__(256, 2)
void gemm_qkv32(const unsigned short* __restrict__ A,
                const unsigned short* __restrict__ Wall,
                unsigned short* __restrict__ qbf,
                unsigned short* __restrict__ kbf,
                unsigned short* __restrict__ vt,
                const float2* __restrict__ tab)
{
  __shared__ __align__(16) char lds[32768];   // 2 slots x 16KB
  const int tid = threadIdx.x;
  const int bid = blockIdx.x;
  const int sel = bid >> 9;
  const int r = bid & 511;
  const int xcd = r & 7, idx = r >> 3;
  const int mt = xcd*8 + (idx >> 3), nt = idx & 7;
  const unsigned short* Bm = Wall + (size_t)sel*DM*DM;
  const int a0 = mt*128, b0r = nt*128;
  const int w = tid>>6, lane = tid&63, ln = lane&15, g = lane>>4;
  const int wm = (w>>1)*64, wn = (w&1)*64;

  // staging: thread covers rows rr, rr+64 of A and B; 16B at col cbyte
  const int rr = tid >> 2;            // 0..63
  const int cbyte = (tid & 3) * 16;   // 0..48 (rows are 64B)
  const char* aS0 = (const char*)(A  + (size_t)(a0 + rr)*DM) + cbyte;
  const char* aS1 = (const char*)(A  + (size_t)(a0 + 64 + rr)*DM) + cbyte;
  const char* bS0 = (const char*)(Bm + (size_t)(b0r + rr)*DM) + cbyte;
  const char* bS1 = (const char*)(Bm + (size_t)(b0r + 64 + rr)*DM) + cbyte;
  const int d0 = rr*64 + cbyte;

  // fragment read offsets (linear, 64B rows)
  int offA[4], offB[4];
  #pragma unroll
  for (int m = 0; m < 4; ++m) {
    offA[m] = (wm + m*16 + ln)*64 + g*16;
    offB[m] = 8192 + (wn + m*16 + ln)*64 + g*16;
  }

  f32x4 acc[4][4];
  #pragma unroll
  for (int i=0;i<4;i++)
    #pragma unroll
    for (int j=0;j<4;j++) acc[i][j] = (f32x4){0.f,0.f,0.f,0.f};

  // prologue: stage tiles 0 -> slot0, 1 -> slot1 (4 loads each)
  {
    gl_lds16(aS0,      lds +         d0);
    gl_lds16(aS1,      lds +  4096 + d0);
    gl_lds16(bS0,      lds +  8192 + d0);
    gl_lds16(bS1,      lds + 12288 + d0);
    gl_lds16(aS0 + 64, lds + 16384 +         d0);
    gl_lds16(aS1 + 64, lds + 16384 +  4096 + d0);
    gl_lds16(bS0 + 64, lds + 16384 +  8192 + d0);
    gl_lds16(bS1 + 64, lds + 16384 + 12288 + d0);
  }

  for (int t = 0; t < NT32; ++t) {
    char* sb = lds + (t & 1) * 16384;
    if (t < NT32-1) asm volatile("s_waitcnt vmcnt(4)" ::: "memory");
    else            asm volatile("s_waitcnt vmcnt(0)" ::: "memory");
    BAR_SYNC();

    bf16x8 fa[4], fb[4];
    #pragma unroll
    for (int m = 0; m < 4; ++m) {
      fa[m] = *(const bf16x8*)(sb + offA[m]);
      fb[m] = *(const bf16x8*)(sb + offB[m]);
    }
    LGKM0();
    BAR_SYNC();

    if (t + 2 < NT32) {
      const size_t kB = (size_t)(t + 2) * 64;
      gl_lds16(aS0 + kB, sb +         d0);
      gl_lds16(aS1 + kB, sb +  4096 + d0);
      gl_lds16(bS0 + kB, sb +  8192 + d0);
      gl_lds16(bS1 + kB, sb + 12288 + d0);
    }
    __builtin_amdgcn_s_setprio(1);
    #pragma unroll
    for (int m = 0; m < 4; ++m)
      #pragma unroll
      for (int n = 0; n < 4; ++n)
        acc[m][n] = mfma16(fa[m], fb[n], acc[m][n]);
    __builtin_amdgcn_s_setprio(0);
  }

  // ---- epilogues (verified R12 formulas) ----
  if (sel == 2) {
    #pragma unroll
    for (int i=0;i<4;i++) {
      int m0 = a0 + wm + i*16 + g*4;
      int bb = m0>>11, s0 = m0&2047;
      #pragma unroll
      for (int jn=0;jn<4;jn++) {
        int n = b0r + wn + jn*16 + ln;
        int h = n>>6, d = n&63;
        ushort4_t o4;
        #pragma unroll
        for (int j=0;j<4;j++) o4[j] = f2bf(acc[i][jn][j]);
        *(ushort4_t*)&vt[(((size_t)bb*NH + h)*DK + d)*SEQ + s0] = o4;
      }
    }
  } else {
    unsigned short* dst = sel ? kbf : qbf;
    const float qs = sel ? 1.0f : 0.1803368802f;   // 1/8 * log2(e) folded into Q
    #pragma unroll
    for (int jn=0;jn<4;jn++) {
      int n = b0r + wn + jn*16 + ln;
      int h = n>>6, d = n&63, di = d>>1, par = d&1;
      #pragma unroll
      for (int i=0;i<4;i++) {
        #pragma unroll
        for (int j=0;j<4;j++) {
          int m = a0 + wm + i*16 + g*4 + j;
          int bb = m>>11, s = m&2047;
          float v = acc[i][jn][j];
          float pv = __shfl_xor(v, 1);
          float2 cssn = tab[s*32 + di];
          float rr2 = par ? (v*cssn.x + pv*cssn.y) : (v*cssn.x - pv*cssn.y);
          dst[((size_t)(bb*NH + h)*SEQ + s)*DK + d] = f2bf(rr2*qs);
        }
      }
    }
  }
}

// ---------------- O-proj GEMM: counted-vmcnt double-buffered 128x128 (R12) ----
__global__ __launch_bounds__(256, 2)
void gemm_ot(const unsigned short* __restrict__ A,
             const unsigned short* __restrict__ Wall,
             float* __restrict__ ofp)
{
  __shared__ __align__(16) char lds[65536];
  const int tid = threadIdx.x;
  const int bid = blockIdx.x;
  int xcd = bid & 7, idx = bid >> 3;
  int mt = xcd*8 + (idx >> 3), nt = idx & 7;
  const unsigned short* Bm = Wall + (size_t)3*DM*DM;
  const int a0 = mt*128, b0r = nt*128;
  const int w = tid>>6, lane = tid&63, ln = lane&15, g = lane>>4;
  const int wm = (w>>1)*64, wn = (w&1)*64;

  const char* src[8];
  {
    int rr = tid >> 3;
    int c  = (tid & 7) * 8;
    #pragma unroll
    for (int i = 0; i < 4; ++i) {
      int r_ = i*32 + rr;
      int cs = c ^ swz_of(r_);
      src[i]   = (const char*)(A  + (size_t)(a0  + r_)*DM + cs);
      src[i+4] = (const char*)(Bm + (size_t)(b0r + r_)*DM + cs);
    }
  }

  int offA[4], offB[4];
  #pragma unroll
  for (int m = 0; m < 4; ++m) {
    int R  = wm + m*16 + ln;
    offA[m] = R*128 + ((g*8 ^ swz_of(R)) * 2);
    int Rb = wn + m*16 + ln;
    offB[m] = 16384 + Rb*128 + ((g*8 ^ swz_of(Rb)) * 2);
  }

  f32x4 acc[4][4];
  #pragma unroll
  for (int i=0;i<4;i++)
    #pragma unroll
    for (int j=0;j<4;j++) acc[i][j] = (f32x4){0.f,0.f,0.f,0.f};

  #pragma unroll
  for (int i = 0; i < 8; ++i) gl_lds16(src[i],       lds +         i*4096 + tid*16);
  #pragma unroll
  for (int i = 0; i < 8; ++i) gl_lds16(src[i] + 128, lds + 32768 + i*4096 + tid*16);

  for (int t = 0; t < NTK; ++t) {
    char* sb = lds + (t & 1) * 32768;
    if (t < NTK-1) asm volatile("s_waitcnt vmcnt(8)" ::: "memory");
    else           asm volatile("s_waitcnt vmcnt(0)" ::: "memory");
    BAR_SYNC();

    bf16x8 fa[4][2], fb[4][2];
    #pragma unroll
    for (int m = 0; m < 4; ++m) {
      fa[m][0] = *(const bf16x8*)(sb + offA[m]);
      fa[m][1] = *(const bf16x8*)(sb + (offA[m] ^ 64));
      fb[m][0] = *(const bf16x8*)(sb + offB[m]);
      fb[m][1] = *(const bf16x8*)(sb + (offB[m] ^ 64));
    }
    LGKM0();
    BAR_SYNC();

    if (t + 2 < NTK) {
      const int kb = (t + 2) * 128;
      #pragma unroll
      for (int i = 0; i < 8; ++i)
        gl_lds16(src[i] + kb, sb + i*4096 + tid*16);
    }
    __builtin_amdgcn_s_setprio(1);
    #pragma unroll
    for (int h = 0; h < 2; ++h)
      #pragma unroll
      for (int m = 0; m < 4; ++m)
        #pragma unroll
        for (int n = 0; n < 4; ++n)
          acc[m][n] = mfma16(fa[m][h], fb[n][h], acc[m][n]);
    __builtin_amdgcn_s_setprio(0);
  }

  #pragma unroll
  for (int i=0;i<4;i++) {
    int m = a0 + wm + i*16 + g*4;
    #pragma unroll
    for (int jn=0;jn<4;jn++) {
      int n = b0r + wn + jn*16 + ln;
      #pragma unroll
      for (int j=0;j<4;j++)
        ofp[(size_t)(m+j)*DM + n] = acc[i][jn][j];
    }
  }
}

// ---------------- flash attention: static-max softmax (R12, unchanged) --------
__global__ __launch_bounds__(128, 2)
void attn_fa(const unsigned short* __restrict__ qbf,
             const unsigned short* __restrict__ kbf,
             const unsigned short* __restrict__ vtg,
             unsigned short* __restrict__ attnbf)
{
  __shared__ __align__(16) char kv_lds[32768];
  __shared__ __align__(16) char pl_lds[4096];
  const int bh = blockIdx.x, pr = blockIdx.y;
  const int qbA = 31 - pr;
  const int NTa = qbA + 1;
  const int NTtot = 33;
  const int tid = threadIdx.x, w = tid>>6, lane = tid&63, ln = lane&15, g = lane>>4;
  const int bb = bh>>4, h = bh&15;

  uint4_t ov = {0x3F803F80u, 0x3F803F80u, 0x3F803F80u, 0x3F803F80u};
  const bf16x8 ones = *(bf16x8*)&ov;

  const int rr = tid >> 3;
  const int cb = (tid & 7) * 16;
  const char* ks[4]; const char* vs[4];
  #pragma unroll
  for (int i = 0; i < 4; ++i) {
    int row = rr + i*16;
    ks[i] = (const char*)(kbf + ((size_t)bh*SEQ + row)*DK) + (cb ^ bswz(row));
    vs[i] = (const char*)(vtg + ((size_t)bh*DK  + row)*SEQ) + (cb ^ bswz(row));
  }

  const int ok0 = (g*16) ^ bswz(ln);
  char* plw = pl_lds + w*2048 + ln*128;
  const int plswz = (ln & 7) << 4;

  #pragma unroll
  for (int i = 0; i < 4; ++i) {
    gl_lds16(ks[i], kv_lds + i*2048 + tid*16);
    gl_lds16(vs[i], kv_lds + 8192 + i*2048 + tid*16);
  }
  #pragma unroll
  for (int i = 0; i < 4; ++i) {
    gl_lds16(ks[i] + 8192, kv_lds + 16384 + i*2048 + tid*16);
    gl_lds16(vs[i] + 128,  kv_lds + 16384 + 8192 + i*2048 + tid*16);
  }

  int q0a = qbA*64 + w*32;
  int q0b = q0a + 16;
  const unsigned short* qrA = qbf + ((size_t)bh*SEQ + q0a + ln)*DK;
  const unsigned short* qrB = qbf + ((size_t)bh*SEQ + q0b + ln)*DK;
  bf16x8 qa0 = *(const bf16x8*)(qrA + g*8);
  bf16x8 qa1 = *(const bf16x8*)(qrA + 32 + g*8);
  bf16x8 qb0 = *(const bf16x8*)(qrB + g*8);
  bf16x8 qb1 = *(const bf16x8*)(qrB + 32 + g*8);

  f32x4 oA[4], oB[4], osA, osB;
  #pragma unroll
  for (int f=0;f<4;f++) { oA[f] = (f32x4){0,0,0,0}; oB[f] = (f32x4){0,0,0,0}; }
  osA = (f32x4){0,0,0,0}; osB = (f32x4){0,0,0,0};

  for (int u = 0; u < NTtot; ++u) {
    const int tloc  = (u < NTa) ? u : u - NTa;
    const int NTcur = (u < NTa) ? NTa : NTtot - NTa;
    char* sb = kv_lds + (u & 1) * 16384;
    if (u < NTtot-1) asm volatile("s_waitcnt vmcnt(8)" ::: "memory");
    else             asm volatile("s_waitcnt vmcnt(0)" ::: "memory");
    BAR_SYNC();

    bf16x8 kf[4][2], vfr[4][2];
    #pragma unroll
    for (int a=0;a<4;a++) {
      kf[a][0]  = *(const bf16x8*)(sb + a*2048 + (ok0 ^  0) + ln*128);
      kf[a][1]  = *(const bf16x8*)(sb + a*2048 + (ok0 ^ 64) + ln*128);
      vfr[a][0] = *(const bf16x8*)(sb + 8192 + a*2048 + (ok0 ^  0) + ln*128);
      vfr[a][1] = *(const bf16x8*)(sb + 8192 + a*2048 + (ok0 ^ 64) + ln*128);
    }
    LGKM0();
    BAR_SYNC();

    if (u + 2 < NTtot) {
      const int t2 = (u + 2 < NTa) ? u + 2 : u + 2 - NTa;
      const size_t kO = (size_t)t2*8192, vO = (size_t)t2*128;
      #pragma unroll
      for (int i = 0; i < 4; ++i) {
        gl_lds16(ks[i] + kO, sb + i*2048 + tid*16);
        gl_lds16(vs[i] + vO, sb + 8192 + i*2048 + tid*16);
      }
    }

    if (u == NTa) {
      #pragma unroll
      for (int j=0;j<4;j++) {
        float liA = 1.0f / osA[j];
        float liB = 1.0f / osB[j];
        int sA = q0a + g*4 + j, sB = q0b + g*4 + j;
        #pragma unroll
        for (int f=0;f<4;f++) {
          attnbf[((size_t)bb*SEQ + sA)*DM + h*DK + f*16 + ln] = f2bf(oA[f][j]*liA);
          attnbf[((size_t)bb*SEQ + sB)*DM + h*DK + f*16 + ln] = f2bf(oB[f][j]*liB);
        }
      }
      q0a = pr*64 + w*32;
      q0b = q0a + 16;
      const unsigned short* qa = qbf + ((size_t)bh*SEQ + q0a + ln)*DK;
      const unsigned short* qb = qbf + ((size_t)bh*SEQ + q0b + ln)*DK;
      qa0 = *(const bf16x8*)(qa + g*8);
      qa1 = *(const bf16x8*)(qa + 32 + g*8);
      qb0 = *(const bf16x8*)(qb + g*8);
      qb1 = *(const bf16x8*)(qb + 32 + g*8);
      #pragma unroll
      for (int f=0;f<4;f++) { oA[f] = (f32x4){0,0,0,0}; oB[f] = (f32x4){0,0,0,0}; }
      osA = (f32x4){0,0,0,0}; osB = (f32x4){0,0,0,0};
    }

    f32x4 saA[4], saB[4];
    __builtin_amdgcn_s_setprio(1);
    #pragma unroll
    for (int kvf=0;kvf<4;kvf++) {
      f32x4 za = (f32x4){0,0,0,0};
      za = mfma16(kf[kvf][0], qa0, za);
      za = mfma16(kf[kvf][1], qa1, za);
      saA[kvf] = za;
      f32x4 zb = (f32x4){0,0,0,0};
      zb = mfma16(kf[kvf][0], qb0, zb);
      zb = mfma16(kf[kvf][1], qb1, zb);
      saB[kvf] = zb;
    }
    __builtin_amdgcn_s_setprio(0);

    const bool diag = (tloc == NTcur-1);

    {
      if (diag) {
        int thr = q0a + ln - tloc*64 - g*4;
        #pragma unroll
        for (int kvf=0;kvf<4;kvf++)
          #pragma unroll
          for (int j=0;j<4;j++)
            if (kvf*16 + j > thr) saA[kvf][j] = -1e30f;
      }
      #pragma unroll
      for (int kvf=0;kvf<4;kvf++) {
        float p0 = fexp2(saA[kvf][0]);
        float p1 = fexp2(saA[kvf][1]);
        float p2 = fexp2(saA[kvf][2]);
        float p3 = fexp2(saA[kvf][3]);
        uint2 pk;
        pk.x = cvt_pk_bf16(p0, p1);
        pk.y = cvt_pk_bf16(p2, p3);
        *(uint2*)(plw + ((kvf*32 + g*8) ^ plswz)) = pk;
      }
      asm volatile("s_waitcnt lgkmcnt(0)" ::: "memory");
      __builtin_amdgcn_sched_barrier(0);
      #pragma unroll
      for (int c=0;c<2;c++) {
        bf16x8 pfA = *(const bf16x8*)(plw + ((c*64 + g*16) ^ plswz));
        #pragma unroll
        for (int f=0;f<4;f++)
          oA[f] = mfma16(pfA, vfr[f][c], oA[f]);
        osA = mfma16(pfA, ones, osA);
      }
    }

    {
      if (diag) {
        int thr = q0b + ln - tloc*64 - g*4;
        #pragma unroll
        for (int kvf=0;kvf<4;kvf++)
          #pragma unroll
          for (int j=0;j<4;j++)
            if (kvf*16 + j > thr) saB[kvf][j] = -1e30f;
      }
      #pragma unroll
      for (int kvf=0;kvf<4;kvf++) {
        float p0 = fexp2(saB[kvf][0]);
        float p1 = fexp2(saB[kvf][1]);
        float p2 = fexp2(saB[kvf][2]);
        float p3 = fexp2(saB[kvf][3]);
        uint2 pk;
        pk.x = cvt_pk_bf16(p0, p1);
        pk.y = cvt_pk_bf16(p2, p3);
        *(uint2*)(plw + ((kvf*32 + g*8) ^ plswz)) = pk;
      }
      asm volatile("s_waitcnt lgkmcnt(0)" ::: "memory");
      __builtin_amdgcn_sched_barrier(0);
      __builtin_amdgcn_s_setprio(1);
      #pragma unroll
      for (int c=0;c<2;c++) {
        bf16x8 pfB = *(const bf16x8*)(plw + ((c*64 + g*16) ^ plswz));
        #pragma unroll
        for (int f=0;f<4;f++)
          oB[f] = mfma16(pfB, vfr[f][c], oB[f]);
        osB = mfma16(pfB, ones, osB);
      }
      __builtin_amdgcn_s_setprio(0);
    }
  }

  #pragma unroll
  for (int j=0;j<4;j++) {
    float liA = 1.0f / osA[j];
    float liB = 1.0f / osB[j];
    int sA = q0a + g*4 + j, sB = q0b + g*4 + j;
    #pragma unroll
    for (int f=0;f<4;f++) {
      attnbf[((size_t)bb*SEQ + sA)*DM + h*DK + f*16 + ln] = f2bf(oA[f][j]*liA);
      attnbf[((size_t)bb*SEQ + sB)*DM + h*DK + f*16 + ln] = f2bf(oB[f][j]*liB);
    }
  }
}

// ---------------- launch ----------------
extern "C" void kernel_launch(void* const* d_in, const int* in_sizes, int n_in,
                              void* d_out, int out_size, void* d_ws, size_t ws_size,
                              hipStream_t stream)
{
  const float* x  = (const float*)d_in[0];
  const float* wq = (const float*)d_in[1];
  const float* wk = (const float*)d_in[2];
  const float* wv = (const float*)d_in[3];
  const float* wo = (const float*)d_in[4];
  const int*   tp = (const int*)d_in[5];

  const size_t XB = (size_t)BATCH*SEQ*DM*2;
  const size_t WB = (size_t)DM*DM*2;

  char* ws = (char*)d_ws;
  unsigned short* xbf = (unsigned short*)(ws);
  unsigned short* qbf = (unsigned short*)(ws + XB);
  unsigned short* kbf = (unsigned short*)(ws + 2*XB);
  unsigned short* vt  = (unsigned short*)(ws + 3*XB);
  unsigned short* abf = (unsigned short*)(ws + 4*XB);
  unsigned short* wbf = (unsigned short*)(ws + 5*XB);
  float2* tab = (float2*)(ws + 5*XB + 4*WB);

  prep_kernel<<<12544, 256, 0, stream>>>(x, wq, wk, wv, wo, tp, xbf, wbf, tab);

  // QKV: BK=32 m97-geometry, 4 blocks/CU
  gemm_qkv32<<<1536, 256, 0, stream>>>(xbf, wbf, qbf, kbf, vt, tab);
  // attention
  attn_fa<<<dim3(64,16), 128, 0, stream>>>(qbf, kbf, vt, abf);
  // O-proj
  gemm_ot<<<512, 256, 0, stream>>>(abf, wbf, (float*)d_out);
}

// Round 17
// 162.531 us; speedup vs baseline: 1.5168x; 1.0425x over previous
//
#include <hip/hip_runtime.h>
#include <hip/hip_bf16.h>
#include <stdint.h>

#define DM   1024
#define SEQ  2048
#define BATCH 4
#define NH   16
#define DK   64
#define NTK  16    // K=1024 / BK=64

typedef __attribute__((ext_vector_type(8))) __bf16 bf16x8;
typedef __attribute__((ext_vector_type(4))) float f32x4;
typedef __attribute__((ext_vector_type(4))) unsigned short ushort4_t;
typedef __attribute__((ext_vector_type(4))) unsigned int uint4_t;

typedef __attribute__((address_space(1))) const unsigned int GU32;
typedef __attribute__((address_space(3))) unsigned int LU32;

__device__ inline void gl_lds16(const void* g, void* l) {
  __builtin_amdgcn_global_load_lds((GU32*)g, (LU32*)l, 16, 0, 0);
}

__device__ inline f32x4 mfma16(bf16x8 a, bf16x8 b, f32x4 c) {
  return __builtin_amdgcn_mfma_f32_16x16x32_bf16(a, b, c, 0, 0, 0);
}

__device__ inline unsigned short f2bf(float f) {
  unsigned u = __float_as_uint(f);
  u += 0x7fffu + ((u >> 16) & 1u);
  return (unsigned short)(u >> 16);
}

__device__ inline unsigned cvt_pk_bf16(float a, float b) {
  unsigned r;
  asm("v_cvt_pk_bf16_f32 %0, %1, %2" : "=v"(r) : "v"(a), "v"(b));
  return r;  // lo = bf16(a), hi = bf16(b)
}

__device__ inline float fexp2(float x) {
  float r;
  asm("v_exp_f32 %0, %1" : "=v"(r) : "v"(x));
  return r;
}

// element-space chunk swizzle (GEMM tiles)
__device__ inline int swz_of(int r) { return ((r & 6) << 2) | ((r & 1) << 5); }
// byte-space version (attn K/V tiles)
__device__ inline int bswz(int r) { return ((r & 6) << 3) | ((r & 1) << 6); }

#define BAR_SYNC() do { \
  __builtin_amdgcn_sched_barrier(0); \
  __builtin_amdgcn_s_barrier(); \
  asm volatile("" ::: "memory"); \
  __builtin_amdgcn_sched_barrier(0); } while(0)
#define LGKM0() do { \
  asm volatile("s_waitcnt lgkmcnt(0)" ::: "memory"); \
  __builtin_amdgcn_sched_barrier(0); } while(0)

// ---------------- prep: fp32 -> bf16 conversions + rope table ----------------
__global__ void prep_kernel(const float* __restrict__ x,
                            const float* __restrict__ wq, const float* __restrict__ wk,
                            const float* __restrict__ wv, const float* __restrict__ wo,
                            const int* __restrict__ tp,
                            unsigned short* __restrict__ xbf,
                            unsigned short* __restrict__ wbf,
                            float2* __restrict__ tab)
{
  const int NX4 = (BATCH*SEQ*DM)/4;
  const int NW4 = (DM*DM)/4;
  int idx = blockIdx.x*256 + threadIdx.x;
  if (idx < NX4) {
    float4 v = ((const float4*)x)[idx];
    ushort4_t o; o[0]=f2bf(v.x); o[1]=f2bf(v.y); o[2]=f2bf(v.z); o[3]=f2bf(v.w);
    ((ushort4_t*)xbf)[idx] = o;
  } else if (idx < NX4 + 4*NW4) {
    int t = idx - NX4;
    int wsel = t >> 18;
    int off = t & (NW4-1);
    const float* src = (wsel==0) ? wq : (wsel==1) ? wk : (wsel==2) ? wv : wo;
    float4 v = ((const float4*)src)[off];
    ushort4_t o; o[0]=f2bf(v.x); o[1]=f2bf(v.y); o[2]=f2bf(v.z); o[3]=f2bf(v.w);
    ((ushort4_t*)wbf)[wsel*NW4 + off] = o;
  } else {
    int t = idx - NX4 - 4*NW4;
    if (t < SEQ*32) {
      int s = t >> 5, i = t & 31;
      float invf = exp2f(-(float)i * (13.287712379549449f/32.0f));
      float ang = (float)tp[s] * invf;
      float sn, cs; sincosf(ang, &sn, &cs);
      tab[t] = make_float2(cs, sn);
    }
  }
}

// ---------------- GEMM: counted-vmcnt double-buffered 128x128, BK=64 ---------
// MODE 0: fused QKV (grid 1536 = 3 sel x 512, sel-major XCD-chunked);
// MODE 1: O-proj (grid 512) -> fp32 d_out.  88 VGPR, no spill (verified R12).
template<int MODE>
__global__ __launch_bounds__(256, 2)
void gemm_db(const unsigned short* __restrict__ A,
             const unsigned short* __restrict__ Wall,
             unsigned short* __restrict__ qbf,
             unsigned short* __restrict__ kbf,
             unsigned short* __restrict__ vt,
             float* __restrict__ ofp,
             const float2* __restrict__ tab)
{
  __shared__ __align__(16) char lds[65536];
  const int tid = threadIdx.x;
  const int bid = blockIdx.x;
  int sel, mt, nt;
  if (MODE == 0) {
    sel = bid >> 9;
    int r = bid & 511;
    int xcd = r & 7, idx = r >> 3;
    mt = xcd*8 + (idx >> 3);  nt = idx & 7;
  } else {
    sel = 3;
    int xcd = bid & 7, idx = bid >> 3;
    mt = xcd*8 + (idx >> 3);  nt = idx & 7;
  }
  const unsigned short* Bm = Wall + (size_t)sel*DM*DM;
  const int a0 = mt*128, b0r = nt*128;
  const int w = tid>>6, lane = tid&63, ln = lane&15, g = lane>>4;
  const int wm = (w>>1)*64, wn = (w&1)*64;

  const char* src[8];
  {
    int rr = tid >> 3;
    int c  = (tid & 7) * 8;
    #pragma unroll
    for (int i = 0; i < 4; ++i) {
      int r_ = i*32 + rr;
      int cs = c ^ swz_of(r_);
      src[i]   = (const char*)(A  + (size_t)(a0  + r_)*DM + cs);
      src[i+4] = (const char*)(Bm + (size_t)(b0r + r_)*DM + cs);
    }
  }

  int offA[4], offB[4];
  #pragma unroll
  for (int m = 0; m < 4; ++m) {
    int R  = wm + m*16 + ln;
    offA[m] = R*128 + ((g*8 ^ swz_of(R)) * 2);
    int Rb = wn + m*16 + ln;
    offB[m] = 16384 + Rb*128 + ((g*8 ^ swz_of(Rb)) * 2);
  }

  f32x4 acc[4][4];
  #pragma unroll
  for (int i=0;i<4;i++)
    #pragma unroll
    for (int j=0;j<4;j++) acc[i][j] = (f32x4){0.f,0.f,0.f,0.f};

  #pragma unroll
  for (int i = 0; i < 8; ++i) gl_lds16(src[i],       lds +         i*4096 + tid*16);
  #pragma unroll
  for (int i = 0; i < 8; ++i) gl_lds16(src[i] + 128, lds + 32768 + i*4096 + tid*16);

  for (int t = 0; t < NTK; ++t) {
    char* sb = lds + (t & 1) * 32768;
    if (t < NTK-1) asm volatile("s_waitcnt vmcnt(8)" ::: "memory");
    else           asm volatile("s_waitcnt vmcnt(0)" ::: "memory");
    BAR_SYNC();

    bf16x8 fa[4][2], fb[4][2];
    #pragma unroll
    for (int m = 0; m < 4; ++m) {
      fa[m][0] = *(const bf16x8*)(sb + offA[m]);
      fa[m][1] = *(const bf16x8*)(sb + (offA[m] ^ 64));
      fb[m][0] = *(const bf16x8*)(sb + offB[m]);
      fb[m][1] = *(const bf16x8*)(sb + (offB[m] ^ 64));
    }
    LGKM0();
    BAR_SYNC();

    if (t + 2 < NTK) {
      const int kb = (t + 2) * 128;
      #pragma unroll
      for (int i = 0; i < 8; ++i)
        gl_lds16(src[i] + kb, sb + i*4096 + tid*16);
    }
    __builtin_amdgcn_s_setprio(1);
    #pragma unroll
    for (int h = 0; h < 2; ++h)
      #pragma unroll
      for (int m = 0; m < 4; ++m)
        #pragma unroll
        for (int n = 0; n < 4; ++n)
          acc[m][n] = mfma16(fa[m][h], fb[n][h], acc[m][n]);
    __builtin_amdgcn_s_setprio(0);
  }

  if (MODE == 1) {
    #pragma unroll
    for (int i=0;i<4;i++) {
      int m = a0 + wm + i*16 + g*4;
      #pragma unroll
      for (int jn=0;jn<4;jn++) {
        int n = b0r + wn + jn*16 + ln;
        #pragma unroll
        for (int j=0;j<4;j++)
          ofp[(size_t)(m+j)*DM + n] = acc[i][jn][j];
      }
    }
  } else if (sel == 2) {
    #pragma unroll
    for (int i=0;i<4;i++) {
      int m0 = a0 + wm + i*16 + g*4;
      int bb = m0>>11, s0 = m0&2047;
      #pragma unroll
      for (int jn=0;jn<4;jn++) {
        int n = b0r + wn + jn*16 + ln;
        int h = n>>6, d = n&63;
        ushort4_t o4;
        #pragma unroll
        for (int j=0;j<4;j++) o4[j] = f2bf(acc[i][jn][j]);
        *(ushort4_t*)&vt[(((size_t)bb*NH + h)*DK + d)*SEQ + s0] = o4;
      }
    }
  } else {
    unsigned short* dst = sel ? kbf : qbf;
    const float qs = sel ? 1.0f : 0.1803368802f;   // 1/8 * log2(e) folded into Q
    #pragma unroll
    for (int jn=0;jn<4;jn++) {
      int n = b0r + wn + jn*16 + ln;
      int h = n>>6, d = n&63, di = d>>1, par = d&1;
      #pragma unroll
      for (int i=0;i<4;i++) {
        #pragma unroll
        for (int j=0;j<4;j++) {
          int m = a0 + wm + i*16 + g*4 + j;
          int bb = m>>11, s = m&2047;
          float v = acc[i][jn][j];
          float pv = __shfl_xor(v, 1);
          float2 cssn = tab[s*32 + di];
          float r = par ? (v*cssn.x + pv*cssn.y) : (v*cssn.x - pv*cssn.y);
          dst[((size_t)(bb*NH + h)*SEQ + s)*DK + d] = f2bf(r*qs);
        }
      }
    }
  }
}

// ---------------- flash attention: static-max softmax (R12, verified) ---------
__global__ __launch_bounds__(128, 2)
void attn_fa(const unsigned short* __restrict__ qbf,
             const unsigned short* __restrict__ kbf,
             const unsigned short* __restrict__ vtg,
             unsigned short* __restrict__ attnbf)
{
  __shared__ __align__(16) char kv_lds[32768];
  __shared__ __align__(16) char pl_lds[4096];
  const int bh = blockIdx.x, pr = blockIdx.y;
  const int qbA = 31 - pr;
  const int NTa = qbA + 1;
  const int NTtot = 33;
  const int tid = threadIdx.x, w = tid>>6, lane = tid&63, ln = lane&15, g = lane>>4;
  const int bb = bh>>4, h = bh&15;

  uint4_t ov = {0x3F803F80u, 0x3F803F80u, 0x3F803F80u, 0x3F803F80u};
  const bf16x8 ones = *(bf16x8*)&ov;

  const int rr = tid >> 3;
  const int cb = (tid & 7) * 16;
  const char* ks[4]; const char* vs[4];
  #pragma unroll
  for (int i = 0; i < 4; ++i) {
    int row = rr + i*16;
    ks[i] = (const char*)(kbf + ((size_t)bh*SEQ + row)*DK) + (cb ^ bswz(row));
    vs[i] = (const char*)(vtg + ((size_t)bh*DK  + row)*SEQ) + (cb ^ bswz(row));
  }

  const int ok0 = (g*16) ^ bswz(ln);
  char* plw = pl_lds + w*2048 + ln*128;
  const int plswz = (ln & 7) << 4;

  #pragma unroll
  for (int i = 0; i < 4; ++i) {
    gl_lds16(ks[i], kv_lds + i*2048 + tid*16);
    gl_lds16(vs[i], kv_lds + 8192 + i*2048 + tid*16);
  }
  #pragma unroll
  for (int i = 0; i < 4; ++i) {
    gl_lds16(ks[i] + 8192, kv_lds + 16384 + i*2048 + tid*16);
    gl_lds16(vs[i] + 128,  kv_lds + 16384 + 8192 + i*2048 + tid*16);
  }

  int q0a = qbA*64 + w*32;
  int q0b = q0a + 16;
  const unsigned short* qrA = qbf + ((size_t)bh*SEQ + q0a + ln)*DK;
  const unsigned short* qrB = qbf + ((size_t)bh*SEQ + q0b + ln)*DK;
  bf16x8 qa0 = *(const bf16x8*)(qrA + g*8);
  bf16x8 qa1 = *(const bf16x8*)(qrA + 32 + g*8);
  bf16x8 qb0 = *(const bf16x8*)(qrB + g*8);
  bf16x8 qb1 = *(const bf16x8*)(qrB + 32 + g*8);

  f32x4 oA[4], oB[4], osA, osB;
  #pragma unroll
  for (int f=0;f<4;f++) { oA[f] = (f32x4){0,0,0,0}; oB[f] = (f32x4){0,0,0,0}; }
  osA = (f32x4){0,0,0,0}; osB = (f32x4){0,0,0,0};

  for (int u = 0; u < NTtot; ++u) {
    const int tloc  = (u < NTa) ? u : u - NTa;
    const int NTcur = (u < NTa) ? NTa : NTtot - NTa;
    char* sb = kv_lds + (u & 1) * 16384;
    if (u < NTtot-1) asm volatile("s_waitcnt vmcnt(8)" ::: "memory");
    else             asm volatile("s_waitcnt vmcnt(0)" ::: "memory");
    BAR_SYNC();

    bf16x8 kf[4][2], vfr[4][2];
    #pragma unroll
    for (int a=0;a<4;a++) {
      kf[a][0]  = *(const bf16x8*)(sb + a*2048 + (ok0 ^  0) + ln*128);
      kf[a][1]  = *(const bf16x8*)(sb + a*2048 + (ok0 ^ 64) + ln*128);
      vfr[a][0] = *(const bf16x8*)(sb + 8192 + a*2048 + (ok0 ^  0) + ln*128);
      vfr[a][1] = *(const bf16x8*)(sb + 8192 + a*2048 + (ok0 ^ 64) + ln*128);
    }
    LGKM0();
    BAR_SYNC();

    if (u + 2 < NTtot) {
      const int t2 = (u + 2 < NTa) ? u + 2 : u + 2 - NTa;
      const size_t kO = (size_t)t2*8192, vO = (size_t)t2*128;
      #pragma unroll
      for (int i = 0; i < 4; ++i) {
        gl_lds16(ks[i] + kO, sb + i*2048 + tid*16);
        gl_lds16(vs[i] + vO, sb + 8192 + i*2048 + tid*16);
      }
    }

    if (u == NTa) {
      #pragma unroll
      for (int j=0;j<4;j++) {
        float liA = 1.0f / osA[j];
        float liB = 1.0f / osB[j];
        int sA = q0a + g*4 + j, sB = q0b + g*4 + j;
        #pragma unroll
        for (int f=0;f<4;f++) {
          attnbf[((size_t)bb*SEQ + sA)*DM + h*DK + f*16 + ln] = f2bf(oA[f][j]*liA);
          attnbf[((size_t)bb*SEQ + sB)*DM + h*DK + f*16 + ln] = f2bf(oB[f][j]*liB);
        }
      }
      q0a = pr*64 + w*32;
      q0b = q0a + 16;
      const unsigned short* qa = qbf + ((size_t)bh*SEQ + q0a + ln)*DK;
      const unsigned short* qb = qbf + ((size_t)bh*SEQ + q0b + ln)*DK;
      qa0 = *(const bf16x8*)(qa + g*8);
      qa1 = *(const bf16x8*)(qa + 32 + g*8);
      qb0 = *(const bf16x8*)(qb + g*8);
      qb1 = *(const bf16x8*)(qb + 32 + g*8);
      #pragma unroll
      for (int f=0;f<4;f++) { oA[f] = (f32x4){0,0,0,0}; oB[f] = (f32x4){0,0,0,0}; }
      osA = (f32x4){0,0,0,0}; osB = (f32x4){0,0,0,0};
    }

    f32x4 saA[4], saB[4];
    __builtin_amdgcn_s_setprio(1);
    #pragma unroll
    for (int kvf=0;kvf<4;kvf++) {
      f32x4 za = (f32x4){0,0,0,0};
      za = mfma16(kf[kvf][0], qa0, za);
      za = mfma16(kf[kvf][1], qa1, za);
      saA[kvf] = za;
      f32x4 zb = (f32x4){0,0,0,0};
      zb = mfma16(kf[kvf][0], qb0, zb);
      zb = mfma16(kf[kvf][1], qb1, zb);
      saB[kvf] = zb;
    }
    __builtin_amdgcn_s_setprio(0);

    const bool diag = (tloc == NTcur-1);

    {
      if (diag) {
        int thr = q0a + ln - tloc*64 - g*4;
        #pragma unroll
        for (int kvf=0;kvf<4;kvf++)
          #pragma unroll
          for (int j=0;j<4;j++)
            if (kvf*16 + j > thr) saA[kvf][j] = -1e30f;
      }
      #pragma unroll
      for (int kvf=0;kvf<4;kvf++) {
        float p0 = fexp2(saA[kvf][0]);
        float p1 = fexp2(saA[kvf][1]);
        float p2 = fexp2(saA[kvf][2]);
        float p3 = fexp2(saA[kvf][3]);
        uint2 pk;
        pk.x = cvt_pk_bf16(p0, p1);
        pk.y = cvt_pk_bf16(p2, p3);
        *(uint2*)(plw + ((kvf*32 + g*8) ^ plswz)) = pk;
      }
      asm volatile("s_waitcnt lgkmcnt(0)" ::: "memory");
      __builtin_amdgcn_sched_barrier(0);
      #pragma unroll
      for (int c=0;c<2;c++) {
        bf16x8 pfA = *(const bf16x8*)(plw + ((c*64 + g*16) ^ plswz));
        #pragma unroll
        for (int f=0;f<4;f++)
          oA[f] = mfma16(pfA, vfr[f][c], oA[f]);
        osA = mfma16(pfA, ones, osA);
      }
    }

    {
      if (diag) {
        int thr = q0b + ln - tloc*64 - g*4;
        #pragma unroll
        for (int kvf=0;kvf<4;kvf++)
          #pragma unroll
          for (int j=0;j<4;j++)
            if (kvf*16 + j > thr) saB[kvf][j] = -1e30f;
      }
      #pragma unroll
      for (int kvf=0;kvf<4;kvf++) {
        float p0 = fexp2(saB[kvf][0]);
        float p1 = fexp2(saB[kvf][1]);
        float p2 = fexp2(saB[kvf][2]);
        float p3 = fexp2(saB[kvf][3]);
        uint2 pk;
        pk.x = cvt_pk_bf16(p0, p1);
        pk.y = cvt_pk_bf16(p2, p3);
        *(uint2*)(plw + ((kvf*32 + g*8) ^ plswz)) = pk;
      }
      asm volatile("s_waitcnt lgkmcnt(0)" ::: "memory");
      __builtin_amdgcn_sched_barrier(0);
      __builtin_amdgcn_s_setprio(1);
      #pragma unroll
      for (int c=0;c<2;c++) {
        bf16x8 pfB = *(const bf16x8*)(plw + ((c*64 + g*16) ^ plswz));
        #pragma unroll
        for (int f=0;f<4;f++)
          oB[f] = mfma16(pfB, vfr[f][c], oB[f]);
        osB = mfma16(pfB, ones, osB);
      }
      __builtin_amdgcn_s_setprio(0);
    }
  }

  #pragma unroll
  for (int j=0;j<4;j++) {
    float liA = 1.0f / osA[j];
    float liB = 1.0f / osB[j];
    int sA = q0a + g*4 + j, sB = q0b + g*4 + j;
    #pragma unroll
    for (int f=0;f<4;f++) {
      attnbf[((size_t)bb*SEQ + sA)*DM + h*DK + f*16 + ln] = f2bf(oA[f][j]*liA);
      attnbf[((size_t)bb*SEQ + sB)*DM + h*DK + f*16 + ln] = f2bf(oB[f][j]*liB);
    }
  }
}

// ---------------- launch ----------------
extern "C" void kernel_launch(void* const* d_in, const int* in_sizes, int n_in,
                              void* d_out, int out_size, void* d_ws, size_t ws_size,
                              hipStream_t stream)
{
  const float* x  = (const float*)d_in[0];
  const float* wq = (const float*)d_in[1];
  const float* wk = (const float*)d_in[2];
  const float* wv = (const float*)d_in[3];
  const float* wo = (const float*)d_in[4];
  const int*   tp = (const int*)d_in[5];

  const size_t XB = (size_t)BATCH*SEQ*DM*2;
  const size_t WB = (size_t)DM*DM*2;

  char* ws = (char*)d_ws;
  unsigned short* xbf = (unsigned short*)(ws);
  unsigned short* qbf = (unsigned short*)(ws + XB);
  unsigned short* kbf = (unsigned short*)(ws + 2*XB);
  unsigned short* vt  = (unsigned short*)(ws + 3*XB);
  unsigned short* abf = (unsigned short*)(ws + 4*XB);
  unsigned short* wbf = (unsigned short*)(ws + 5*XB);
  float2* tab = (float2*)(ws + 5*XB + 4*WB);

  prep_kernel<<<12544, 256, 0, stream>>>(x, wq, wk, wv, wo, tp, xbf, wbf, tab);

  gemm_db<0><<<1536, 256, 0, stream>>>(xbf, wbf, qbf, kbf, vt, nullptr, tab);
  attn_fa<<<dim3(64,16), 128, 0, stream>>>(qbf, kbf, vt, abf);
  gemm_db<1><<<512, 256, 0, stream>>>(abf, wbf, nullptr, nullptr, nullptr,
                                      (float*)d_out, nullptr);
}